// Round 1
// baseline (578.193 us; speedup 1.0000x reference)
//
#include <hip/hip_runtime.h>

#define NC 5
#define NJ 4
#define NV 512
#define QSTRIDE 26   // 6 + NC*NJ

// Rodrigues formula for a (unit) axis and angle.
__device__ __forceinline__ void rodrigues_unit(float x, float y, float z,
                                               float ang, float* R) {
    float s, c;
    __sincosf(ang, &s, &c);
    float C = 1.0f - c;
    R[0] = fmaf(x * x, C, c);
    R[1] = fmaf(x * y, C, -z * s);
    R[2] = fmaf(x * z, C,  y * s);
    R[3] = fmaf(y * x, C,  z * s);
    R[4] = fmaf(y * y, C, c);
    R[5] = fmaf(y * z, C, -x * s);
    R[6] = fmaf(z * x, C, -y * s);
    R[7] = fmaf(z * y, C,  x * s);
    R[8] = fmaf(z * z, C, c);
}

__global__ __launch_bounds__(256) void kin_fwd(
        const float* __restrict__ qpos, const float* __restrict__ offsets,
        const float* __restrict__ axes, const float* __restrict__ verts,
        float* __restrict__ out) {
    const int b = blockIdx.x;   // one block per batch element

    __shared__ float sRT[NC * NJ][12];   // per (chain,joint): R (9) + t (3)

    const int t = threadIdx.x;

    // ---- FK phase: 5 chains computed in parallel by threads 0..4 ----
    if (t < NC) {
        const int c = t;
        const float* qp = qpos + (size_t)b * QSTRIDE;
        float T0 = qp[0], T1 = qp[1], T2 = qp[2];
        float ax = qp[3], ay = qp[4], az = qp[5];
        float ang = sqrtf(ax * ax + ay * ay + az * az);
        float inv = 1.0f / fmaxf(ang, 1e-8f);
        float R[9];
        rodrigues_unit(ax * inv, ay * inv, az * inv, ang, R);

        #pragma unroll
        for (int j = 0; j < NJ; j++) {
            const float* off = offsets + (size_t)(c * NJ + j) * 16;
            float o00 = off[0],  o01 = off[1],  o02 = off[2],  ot0 = off[3];
            float o10 = off[4],  o11 = off[5],  o12 = off[6],  ot1 = off[7];
            float o20 = off[8],  o21 = off[9],  o22 = off[10], ot2 = off[11];

            // t_new = R * t_off + t
            float nt0 = T0 + R[0] * ot0 + R[1] * ot1 + R[2] * ot2;
            float nt1 = T1 + R[3] * ot0 + R[4] * ot1 + R[5] * ot2;
            float nt2 = T2 + R[6] * ot0 + R[7] * ot1 + R[8] * ot2;

            // M = R * R_off
            float M[9];
            M[0] = R[0] * o00 + R[1] * o10 + R[2] * o20;
            M[1] = R[0] * o01 + R[1] * o11 + R[2] * o21;
            M[2] = R[0] * o02 + R[1] * o12 + R[2] * o22;
            M[3] = R[3] * o00 + R[4] * o10 + R[5] * o20;
            M[4] = R[3] * o01 + R[4] * o11 + R[5] * o21;
            M[5] = R[3] * o02 + R[4] * o12 + R[5] * o22;
            M[6] = R[6] * o00 + R[7] * o10 + R[8] * o20;
            M[7] = R[6] * o01 + R[7] * o11 + R[8] * o21;
            M[8] = R[6] * o02 + R[7] * o12 + R[8] * o22;

            // Rj from (pre-normalized) joint axis and angle q
            const float* axp = axes + (size_t)(c * NJ + j) * 3;
            float qj = qp[6 + c * NJ + j];
            float Rj[9];
            rodrigues_unit(axp[0], axp[1], axp[2], qj, Rj);

            // R = M * Rj
            R[0] = M[0] * Rj[0] + M[1] * Rj[3] + M[2] * Rj[6];
            R[1] = M[0] * Rj[1] + M[1] * Rj[4] + M[2] * Rj[7];
            R[2] = M[0] * Rj[2] + M[1] * Rj[5] + M[2] * Rj[8];
            R[3] = M[3] * Rj[0] + M[4] * Rj[3] + M[5] * Rj[6];
            R[4] = M[3] * Rj[1] + M[4] * Rj[4] + M[5] * Rj[7];
            R[5] = M[3] * Rj[2] + M[4] * Rj[5] + M[5] * Rj[8];
            R[6] = M[6] * Rj[0] + M[7] * Rj[3] + M[8] * Rj[6];
            R[7] = M[6] * Rj[1] + M[7] * Rj[4] + M[8] * Rj[7];
            R[8] = M[6] * Rj[2] + M[7] * Rj[5] + M[8] * Rj[8];
            T0 = nt0; T1 = nt1; T2 = nt2;

            float* dst = sRT[c * NJ + j];
            #pragma unroll
            for (int k = 0; k < 9; k++) dst[k] = R[k];
            dst[9] = T0; dst[10] = T1; dst[11] = T2;
        }
    }
    __syncthreads();

    // ---- vertex phase: wave w handles pairs p = w, w+4, ..., w+16 ----
    const int wv = t >> 6;            // wave id 0..3
    const int v0 = (t & 63) << 3;     // 8 verts per lane

    #pragma unroll
    for (int p = wv; p < NC * NJ; p += 4) {
        const float* RT = sRT[p];     // wave-uniform LDS broadcast
        float R0 = RT[0], R1 = RT[1], R2 = RT[2];
        float R3 = RT[3], R4 = RT[4], R5 = RT[5];
        float R6 = RT[6], R7 = RT[7], R8 = RT[8];
        float T0 = RT[9], T1 = RT[10], T2 = RT[11];

        const float4* vp =
            (const float4*)(verts + ((size_t)p * NV + v0) * 3);
        float4 i0 = vp[0], i1 = vp[1], i2 = vp[2];
        float4 i3 = vp[3], i4 = vp[4], i5 = vp[5];

        float o[24];
#define XFORM(vx, vy, vz, ox, oy, oz)                       \
        ox = fmaf(R0, vx, fmaf(R1, vy, fmaf(R2, vz, T0)));  \
        oy = fmaf(R3, vx, fmaf(R4, vy, fmaf(R5, vz, T1)));  \
        oz = fmaf(R6, vx, fmaf(R7, vy, fmaf(R8, vz, T2)));

        XFORM(i0.x, i0.y, i0.z, o[0],  o[1],  o[2]);
        XFORM(i0.w, i1.x, i1.y, o[3],  o[4],  o[5]);
        XFORM(i1.z, i1.w, i2.x, o[6],  o[7],  o[8]);
        XFORM(i2.y, i2.z, i2.w, o[9],  o[10], o[11]);
        XFORM(i3.x, i3.y, i3.z, o[12], o[13], o[14]);
        XFORM(i3.w, i4.x, i4.y, o[15], o[16], o[17]);
        XFORM(i4.z, i4.w, i5.x, o[18], o[19], o[20]);
        XFORM(i5.y, i5.z, i5.w, o[21], o[22], o[23]);
#undef XFORM

        float4* op = (float4*)(out +
            ((size_t)(b * NC * NJ + p) * NV + v0) * 3);
        op[0] = make_float4(o[0],  o[1],  o[2],  o[3]);
        op[1] = make_float4(o[4],  o[5],  o[6],  o[7]);
        op[2] = make_float4(o[8],  o[9],  o[10], o[11]);
        op[3] = make_float4(o[12], o[13], o[14], o[15]);
        op[4] = make_float4(o[16], o[17], o[18], o[19]);
        op[5] = make_float4(o[20], o[21], o[22], o[23]);
    }
}

extern "C" void kernel_launch(void* const* d_in, const int* in_sizes, int n_in,
                              void* d_out, int out_size, void* d_ws, size_t ws_size,
                              hipStream_t stream) {
    const float* qpos    = (const float*)d_in[0];
    const float* offsets = (const float*)d_in[1];
    const float* axes    = (const float*)d_in[2];
    const float* verts   = (const float*)d_in[3];
    float* out = (float*)d_out;

    const int B = in_sizes[0] / QSTRIDE;   // 4096
    hipLaunchKernelGGL(kin_fwd, dim3(B), dim3(256), 0, stream,
                       qpos, offsets, axes, verts, out);
}

// Round 2
// 506.495 us; speedup vs baseline: 1.1416x; 1.1416x over previous
//
#include <hip/hip_runtime.h>

#define NC 5
#define NJ 4
#define NV 512
#define QSTRIDE 26   // 6 + NC*NJ

// Rodrigues formula for a (unit) axis and angle.
__device__ __forceinline__ void rodrigues_unit(float x, float y, float z,
                                               float ang, float* R) {
    float s, c;
    __sincosf(ang, &s, &c);
    float C = 1.0f - c;
    R[0] = fmaf(x * x, C, c);
    R[1] = fmaf(x * y, C, -z * s);
    R[2] = fmaf(x * z, C,  y * s);
    R[3] = fmaf(y * x, C,  z * s);
    R[4] = fmaf(y * y, C, c);
    R[5] = fmaf(y * z, C, -x * s);
    R[6] = fmaf(z * x, C, -y * s);
    R[7] = fmaf(z * y, C,  x * s);
    R[8] = fmaf(z * z, C, c);
}

__global__ __launch_bounds__(256) void kin_fwd(
        const float* __restrict__ qpos, const float* __restrict__ offsets,
        const float* __restrict__ axes, const float* __restrict__ verts,
        float* __restrict__ out) {
    const int b = blockIdx.x;   // one block per batch element

    __shared__ float sRT[NC * NJ][12];      // per (chain,joint): R (9) + t (3)
    __shared__ float4 stage[4][6 * 64];     // per-wave 6 KB store-coalescing buffer

    const int t = threadIdx.x;

    // ---- FK phase: 5 chains computed in parallel by threads 0..4 ----
    if (t < NC) {
        const int c = t;
        const float* qp = qpos + (size_t)b * QSTRIDE;
        float T0 = qp[0], T1 = qp[1], T2 = qp[2];
        float ax = qp[3], ay = qp[4], az = qp[5];
        float ang = sqrtf(ax * ax + ay * ay + az * az);
        float inv = 1.0f / fmaxf(ang, 1e-8f);
        float R[9];
        rodrigues_unit(ax * inv, ay * inv, az * inv, ang, R);

        #pragma unroll
        for (int j = 0; j < NJ; j++) {
            const float* off = offsets + (size_t)(c * NJ + j) * 16;
            float o00 = off[0],  o01 = off[1],  o02 = off[2],  ot0 = off[3];
            float o10 = off[4],  o11 = off[5],  o12 = off[6],  ot1 = off[7];
            float o20 = off[8],  o21 = off[9],  o22 = off[10], ot2 = off[11];

            // t_new = R * t_off + t
            float nt0 = T0 + R[0] * ot0 + R[1] * ot1 + R[2] * ot2;
            float nt1 = T1 + R[3] * ot0 + R[4] * ot1 + R[5] * ot2;
            float nt2 = T2 + R[6] * ot0 + R[7] * ot1 + R[8] * ot2;

            // M = R * R_off
            float M[9];
            M[0] = R[0] * o00 + R[1] * o10 + R[2] * o20;
            M[1] = R[0] * o01 + R[1] * o11 + R[2] * o21;
            M[2] = R[0] * o02 + R[1] * o12 + R[2] * o22;
            M[3] = R[3] * o00 + R[4] * o10 + R[5] * o20;
            M[4] = R[3] * o01 + R[4] * o11 + R[5] * o21;
            M[5] = R[3] * o02 + R[4] * o12 + R[5] * o22;
            M[6] = R[6] * o00 + R[7] * o10 + R[8] * o20;
            M[7] = R[6] * o01 + R[7] * o11 + R[8] * o21;
            M[8] = R[6] * o02 + R[7] * o12 + R[8] * o22;

            // Rj from (pre-normalized) joint axis and angle q
            const float* axp = axes + (size_t)(c * NJ + j) * 3;
            float qj = qp[6 + c * NJ + j];
            float Rj[9];
            rodrigues_unit(axp[0], axp[1], axp[2], qj, Rj);

            // R = M * Rj
            R[0] = M[0] * Rj[0] + M[1] * Rj[3] + M[2] * Rj[6];
            R[1] = M[0] * Rj[1] + M[1] * Rj[4] + M[2] * Rj[7];
            R[2] = M[0] * Rj[2] + M[1] * Rj[5] + M[2] * Rj[8];
            R[3] = M[3] * Rj[0] + M[4] * Rj[3] + M[5] * Rj[6];
            R[4] = M[3] * Rj[1] + M[4] * Rj[4] + M[5] * Rj[7];
            R[5] = M[3] * Rj[2] + M[4] * Rj[5] + M[5] * Rj[8];
            R[6] = M[6] * Rj[0] + M[7] * Rj[3] + M[8] * Rj[6];
            R[7] = M[6] * Rj[1] + M[7] * Rj[4] + M[8] * Rj[7];
            R[8] = M[6] * Rj[2] + M[7] * Rj[5] + M[8] * Rj[8];
            T0 = nt0; T1 = nt1; T2 = nt2;

            float* dst = sRT[c * NJ + j];
            #pragma unroll
            for (int k = 0; k < 9; k++) dst[k] = R[k];
            dst[9] = T0; dst[10] = T1; dst[11] = T2;
        }
    }
    __syncthreads();

    // ---- vertex phase: wave w handles pairs p = w, w+4, ..., w+16 ----
    const int wv = t >> 6;            // wave id 0..3
    const int l  = t & 63;            // lane
    const int v0 = l << 3;            // 8 verts per lane
    float4* st = stage[wv];           // private per-wave buffer (no barriers)

    #pragma unroll
    for (int p = wv; p < NC * NJ; p += 4) {
        const float* RT = sRT[p];     // wave-uniform LDS broadcast
        float R0 = RT[0], R1 = RT[1], R2 = RT[2];
        float R3 = RT[3], R4 = RT[4], R5 = RT[5];
        float R6 = RT[6], R7 = RT[7], R8 = RT[8];
        float T0 = RT[9], T1 = RT[10], T2 = RT[11];

        const float4* vp =
            (const float4*)(verts + ((size_t)p * NV + v0) * 3);
        float4 i0 = vp[0], i1 = vp[1], i2 = vp[2];
        float4 i3 = vp[3], i4 = vp[4], i5 = vp[5];

        float o[24];
#define XFORM(vx, vy, vz, ox, oy, oz)                       \
        ox = fmaf(R0, vx, fmaf(R1, vy, fmaf(R2, vz, T0)));  \
        oy = fmaf(R3, vx, fmaf(R4, vy, fmaf(R5, vz, T1)));  \
        oz = fmaf(R6, vx, fmaf(R7, vy, fmaf(R8, vz, T2)));

        XFORM(i0.x, i0.y, i0.z, o[0],  o[1],  o[2]);
        XFORM(i0.w, i1.x, i1.y, o[3],  o[4],  o[5]);
        XFORM(i1.z, i1.w, i2.x, o[6],  o[7],  o[8]);
        XFORM(i2.y, i2.z, i2.w, o[9],  o[10], o[11]);
        XFORM(i3.x, i3.y, i3.z, o[12], o[13], o[14]);
        XFORM(i3.w, i4.x, i4.y, o[15], o[16], o[17]);
        XFORM(i4.z, i4.w, i5.x, o[18], o[19], o[20]);
        XFORM(i5.y, i5.z, i5.w, o[21], o[22], o[23]);
#undef XFORM

        // Stage this wave's 6 KB segment in LDS in exact output (AoS) order.
        st[l * 6 + 0] = make_float4(o[0],  o[1],  o[2],  o[3]);
        st[l * 6 + 1] = make_float4(o[4],  o[5],  o[6],  o[7]);
        st[l * 6 + 2] = make_float4(o[8],  o[9],  o[10], o[11]);
        st[l * 6 + 3] = make_float4(o[12], o[13], o[14], o[15]);
        st[l * 6 + 4] = make_float4(o[16], o[17], o[18], o[19]);
        st[l * 6 + 5] = make_float4(o[20], o[21], o[22], o[23]);

        // Read back lane-contiguous (conflict-free) → fully coalesced stores:
        // each wave store covers 1 KB of contiguous full cache lines.
        float4 r0 = st[0 * 64 + l];
        float4 r1 = st[1 * 64 + l];
        float4 r2 = st[2 * 64 + l];
        float4 r3 = st[3 * 64 + l];
        float4 r4 = st[4 * 64 + l];
        float4 r5 = st[5 * 64 + l];

        float4* op = (float4*)(out + (size_t)(b * NC * NJ + p) * NV * 3);
        op[0 * 64 + l] = r0;
        op[1 * 64 + l] = r1;
        op[2 * 64 + l] = r2;
        op[3 * 64 + l] = r3;
        op[4 * 64 + l] = r4;
        op[5 * 64 + l] = r5;
    }
}

extern "C" void kernel_launch(void* const* d_in, const int* in_sizes, int n_in,
                              void* d_out, int out_size, void* d_ws, size_t ws_size,
                              hipStream_t stream) {
    const float* qpos    = (const float*)d_in[0];
    const float* offsets = (const float*)d_in[1];
    const float* axes    = (const float*)d_in[2];
    const float* verts   = (const float*)d_in[3];
    float* out = (float*)d_out;

    const int B = in_sizes[0] / QSTRIDE;   // 4096
    hipLaunchKernelGGL(kin_fwd, dim3(B), dim3(256), 0, stream,
                       qpos, offsets, axes, verts, out);
}

// Round 3
// 504.954 us; speedup vs baseline: 1.1450x; 1.0031x over previous
//
#include <hip/hip_runtime.h>

#define NC 5
#define NJ 4
#define NV 512
#define QSTRIDE 26   // 6 + NC*NJ
#define NP (NC * NJ)          // 20 (chain,joint) pairs
#define REG_F4 (NV * 3 / 4)   // 384 float4s per (c,j) vert region (6 KB)

// Rodrigues formula for a (unit) axis and angle.
__device__ __forceinline__ void rodrigues_unit(float x, float y, float z,
                                               float ang, float* R) {
    float s, c;
    __sincosf(ang, &s, &c);
    float C = 1.0f - c;
    R[0] = fmaf(x * x, C, c);
    R[1] = fmaf(x * y, C, -z * s);
    R[2] = fmaf(x * z, C,  y * s);
    R[3] = fmaf(y * x, C,  z * s);
    R[4] = fmaf(y * y, C, c);
    R[5] = fmaf(y * z, C, -x * s);
    R[6] = fmaf(z * x, C, -y * s);
    R[7] = fmaf(z * y, C,  x * s);
    R[8] = fmaf(z * z, C, c);
}

// One-shot permute of verts (batch-invariant, 120 KB) so the main kernel's
// per-lane loads are coalesced: ws[p][k*64 + l] = region_p[l*6 + k].
__global__ __launch_bounds__(64) void vert_shuffle(
        const float* __restrict__ verts, float4* __restrict__ ws) {
    const int p = blockIdx.x;        // 0..NP-1
    const int l = threadIdx.x;       // 0..63
    const float4* src = (const float4*)verts + (size_t)p * REG_F4;
    float4*       dst = ws + (size_t)p * REG_F4;
    #pragma unroll
    for (int k = 0; k < 6; k++)
        dst[k * 64 + l] = src[l * 6 + k];
}

template <bool WSVERTS>
__global__ __launch_bounds__(256) void kin_fwd(
        const float* __restrict__ qpos, const float* __restrict__ offsets,
        const float* __restrict__ axes, const float* __restrict__ verts,
        float* __restrict__ out, const float4* __restrict__ vws) {
    const int b = blockIdx.x;   // one block per batch element

    __shared__ float sRT[NP][12];           // per (chain,joint): R (9) + t (3)
    __shared__ float4 stage[4][6 * 64];     // per-wave 6 KB store-coalescing buffer

    const int t = threadIdx.x;

    // ---- FK phase: 5 chains computed in parallel by threads 0..4 ----
    if (t < NC) {
        const int c = t;
        const float* qp = qpos + (size_t)b * QSTRIDE;
        float T0 = qp[0], T1 = qp[1], T2 = qp[2];
        float ax = qp[3], ay = qp[4], az = qp[5];
        float ang = sqrtf(ax * ax + ay * ay + az * az);
        float inv = 1.0f / fmaxf(ang, 1e-8f);
        float R[9];
        rodrigues_unit(ax * inv, ay * inv, az * inv, ang, R);

        #pragma unroll
        for (int j = 0; j < NJ; j++) {
            const float* off = offsets + (size_t)(c * NJ + j) * 16;
            float o00 = off[0],  o01 = off[1],  o02 = off[2],  ot0 = off[3];
            float o10 = off[4],  o11 = off[5],  o12 = off[6],  ot1 = off[7];
            float o20 = off[8],  o21 = off[9],  o22 = off[10], ot2 = off[11];

            // t_new = R * t_off + t
            float nt0 = T0 + R[0] * ot0 + R[1] * ot1 + R[2] * ot2;
            float nt1 = T1 + R[3] * ot0 + R[4] * ot1 + R[5] * ot2;
            float nt2 = T2 + R[6] * ot0 + R[7] * ot1 + R[8] * ot2;

            // M = R * R_off
            float M[9];
            M[0] = R[0] * o00 + R[1] * o10 + R[2] * o20;
            M[1] = R[0] * o01 + R[1] * o11 + R[2] * o21;
            M[2] = R[0] * o02 + R[1] * o12 + R[2] * o22;
            M[3] = R[3] * o00 + R[4] * o10 + R[5] * o20;
            M[4] = R[3] * o01 + R[4] * o11 + R[5] * o21;
            M[5] = R[3] * o02 + R[4] * o12 + R[5] * o22;
            M[6] = R[6] * o00 + R[7] * o10 + R[8] * o20;
            M[7] = R[6] * o01 + R[7] * o11 + R[8] * o21;
            M[8] = R[6] * o02 + R[7] * o12 + R[8] * o22;

            // Rj from (pre-normalized) joint axis and angle q
            const float* axp = axes + (size_t)(c * NJ + j) * 3;
            float qj = qp[6 + c * NJ + j];
            float Rj[9];
            rodrigues_unit(axp[0], axp[1], axp[2], qj, Rj);

            // R = M * Rj
            R[0] = M[0] * Rj[0] + M[1] * Rj[3] + M[2] * Rj[6];
            R[1] = M[0] * Rj[1] + M[1] * Rj[4] + M[2] * Rj[7];
            R[2] = M[0] * Rj[2] + M[1] * Rj[5] + M[2] * Rj[8];
            R[3] = M[3] * Rj[0] + M[4] * Rj[3] + M[5] * Rj[6];
            R[4] = M[3] * Rj[1] + M[4] * Rj[4] + M[5] * Rj[7];
            R[5] = M[3] * Rj[2] + M[4] * Rj[5] + M[5] * Rj[8];
            R[6] = M[6] * Rj[0] + M[7] * Rj[3] + M[8] * Rj[6];
            R[7] = M[6] * Rj[1] + M[7] * Rj[4] + M[8] * Rj[7];
            R[8] = M[6] * Rj[2] + M[7] * Rj[5] + M[8] * Rj[8];
            T0 = nt0; T1 = nt1; T2 = nt2;

            float* dst = sRT[c * NJ + j];
            #pragma unroll
            for (int k = 0; k < 9; k++) dst[k] = R[k];
            dst[9] = T0; dst[10] = T1; dst[11] = T2;
        }
    }
    __syncthreads();

    // ---- vertex phase: wave w handles pairs p = w, w+4, ..., w+16 ----
    const int wv = t >> 6;            // wave id 0..3
    const int l  = t & 63;            // lane
    const int v0 = l << 3;            // 8 verts per lane
    float4* st = stage[wv];           // private per-wave buffer (no barriers)

    #pragma unroll
    for (int p = wv; p < NP; p += 4) {
        const float* RT = sRT[p];     // wave-uniform LDS broadcast
        float R0 = RT[0], R1 = RT[1], R2 = RT[2];
        float R3 = RT[3], R4 = RT[4], R5 = RT[5];
        float R6 = RT[6], R7 = RT[7], R8 = RT[8];
        float T0 = RT[9], T1 = RT[10], T2 = RT[11];

        float4 i0, i1, i2, i3, i4, i5;
        if (WSVERTS) {
            // Pre-permuted: lane l's 8 contiguous verts, loaded coalesced.
            const float4* vp = vws + (size_t)p * REG_F4;
            i0 = vp[0 * 64 + l]; i1 = vp[1 * 64 + l]; i2 = vp[2 * 64 + l];
            i3 = vp[3 * 64 + l]; i4 = vp[4 * 64 + l]; i5 = vp[5 * 64 + l];
        } else {
            const float4* vp =
                (const float4*)(verts + ((size_t)p * NV + v0) * 3);
            i0 = vp[0]; i1 = vp[1]; i2 = vp[2];
            i3 = vp[3]; i4 = vp[4]; i5 = vp[5];
        }

        float o[24];
#define XFORM(vx, vy, vz, ox, oy, oz)                       \
        ox = fmaf(R0, vx, fmaf(R1, vy, fmaf(R2, vz, T0)));  \
        oy = fmaf(R3, vx, fmaf(R4, vy, fmaf(R5, vz, T1)));  \
        oz = fmaf(R6, vx, fmaf(R7, vy, fmaf(R8, vz, T2)));

        XFORM(i0.x, i0.y, i0.z, o[0],  o[1],  o[2]);
        XFORM(i0.w, i1.x, i1.y, o[3],  o[4],  o[5]);
        XFORM(i1.z, i1.w, i2.x, o[6],  o[7],  o[8]);
        XFORM(i2.y, i2.z, i2.w, o[9],  o[10], o[11]);
        XFORM(i3.x, i3.y, i3.z, o[12], o[13], o[14]);
        XFORM(i3.w, i4.x, i4.y, o[15], o[16], o[17]);
        XFORM(i4.z, i4.w, i5.x, o[18], o[19], o[20]);
        XFORM(i5.y, i5.z, i5.w, o[21], o[22], o[23]);
#undef XFORM

        // Stage this wave's 6 KB segment in LDS in exact output (AoS) order.
        st[l * 6 + 0] = make_float4(o[0],  o[1],  o[2],  o[3]);
        st[l * 6 + 1] = make_float4(o[4],  o[5],  o[6],  o[7]);
        st[l * 6 + 2] = make_float4(o[8],  o[9],  o[10], o[11]);
        st[l * 6 + 3] = make_float4(o[12], o[13], o[14], o[15]);
        st[l * 6 + 4] = make_float4(o[16], o[17], o[18], o[19]);
        st[l * 6 + 5] = make_float4(o[20], o[21], o[22], o[23]);

        // Read back lane-contiguous (conflict-free) → fully coalesced stores.
        float4 r0 = st[0 * 64 + l];
        float4 r1 = st[1 * 64 + l];
        float4 r2 = st[2 * 64 + l];
        float4 r3 = st[3 * 64 + l];
        float4 r4 = st[4 * 64 + l];
        float4 r5 = st[5 * 64 + l];

        float4* op = (float4*)(out + (size_t)(b * NP + p) * NV * 3);
        op[0 * 64 + l] = r0;
        op[1 * 64 + l] = r1;
        op[2 * 64 + l] = r2;
        op[3 * 64 + l] = r3;
        op[4 * 64 + l] = r4;
        op[5 * 64 + l] = r5;
    }
}

extern "C" void kernel_launch(void* const* d_in, const int* in_sizes, int n_in,
                              void* d_out, int out_size, void* d_ws, size_t ws_size,
                              hipStream_t stream) {
    const float* qpos    = (const float*)d_in[0];
    const float* offsets = (const float*)d_in[1];
    const float* axes    = (const float*)d_in[2];
    const float* verts   = (const float*)d_in[3];
    float* out = (float*)d_out;

    const int B = in_sizes[0] / QSTRIDE;   // 4096
    const size_t ws_needed = (size_t)NP * REG_F4 * sizeof(float4);  // 120 KB

    if (d_ws != nullptr && ws_size >= ws_needed) {
        hipLaunchKernelGGL(vert_shuffle, dim3(NP), dim3(64), 0, stream,
                           verts, (float4*)d_ws);
        hipLaunchKernelGGL(kin_fwd<true>, dim3(B), dim3(256), 0, stream,
                           qpos, offsets, axes, verts, out,
                           (const float4*)d_ws);
    } else {
        hipLaunchKernelGGL(kin_fwd<false>, dim3(B), dim3(256), 0, stream,
                           qpos, offsets, axes, verts, out,
                           (const float4*)nullptr);
    }
}